// Round 5
// baseline (456.383 us; speedup 1.0000x reference)
//
#include <hip/hip_runtime.h>
#include <math.h>

#define Bq 32
#define Sq 2048
#define Dq 1024
#define Tq 8
#define TILE 64            // S-rows per block in kernel A
#define NT (Sq / TILE)     // 32 tiles per batch row

// ---------------------------------------------------------------------------
// Kernel A: for each 64-row tile of (b):
//   scores[b,s] = dot(qry[b,:], ctx[b,s,:]) + log(mask[b,s])   (written out)
//   partial[b,tile,:] = sum_{s in tile} exp(scores[s] - m_tile) * ctx[b,s,:]
// Each wave owns 16 rows as four 4-row register-resident chunks with online
// max-rescale; cross-wave combine rescales by exp(m_wave - m_tile).
// ctx is read from HBM exactly once for the whole problem.
// Grid (NT, B) = (32, 32) = 1024 blocks, block 256 (4 waves) -> exactly
// 4 blocks/CU at the __launch_bounds__-pinned 128-VGPR occupancy (no tail).
// ---------------------------------------------------------------------------
__global__ __launch_bounds__(256, 4) void fused_scores_partial_kernel(
    const float* __restrict__ qry, const float* __restrict__ ctx,
    const float* __restrict__ mask, float* __restrict__ scores,
    float4* __restrict__ partial)
{
    const int b    = blockIdx.y;
    const int tile = blockIdx.x;
    const int s0   = tile * TILE;
    const int wave = threadIdx.x >> 6;
    const int lane = threadIdx.x & 63;

    __shared__ float  wmax[4];
    __shared__ float4 buf[4 * 256];    // 16 KB wave-partial exchange

    const float4* q4 = (const float4*)(qry + (size_t)b * Dq);
    float4 q[4];
#pragma unroll
    for (int k = 0; k < 4; ++k) q[k] = q4[lane + 64 * k];

    float4 pacc[4];
#pragma unroll
    for (int k = 0; k < 4; ++k) pacc[k] = make_float4(0.f, 0.f, 0.f, 0.f);
    float mw = -INFINITY;

#pragma unroll
    for (int p = 0; p < 4; ++p) {
        const int sbase = s0 + wave * 16 + p * 4;

        float4 c[4][4];
#pragma unroll
        for (int r = 0; r < 4; ++r) {
            const float4* c4 = (const float4*)(ctx + ((size_t)b * Sq + sbase + r) * Dq);
#pragma unroll
            for (int k = 0; k < 4; ++k) c[r][k] = c4[lane + 64 * k];
        }

        float sc[4];
#pragma unroll
        for (int r = 0; r < 4; ++r) {
            float acc = 0.f;
#pragma unroll
            for (int k = 0; k < 4; ++k)
                acc += q[k].x * c[r][k].x + q[k].y * c[r][k].y
                     + q[k].z * c[r][k].z + q[k].w * c[r][k].w;
#pragma unroll
            for (int off = 1; off < 64; off <<= 1)   // butterfly: all lanes get sum
                acc += __shfl_xor(acc, off, 64);
            acc += logf(mask[(size_t)b * Sq + sbase + r]);
            sc[r] = acc;
            if (lane == 0) scores[(size_t)b * Sq + sbase + r] = acc;
        }

        float mc = fmaxf(fmaxf(sc[0], sc[1]), fmaxf(sc[2], sc[3]));
        const float mnew = fmaxf(mw, mc);
        const float scale = (p == 0) ? 0.f : expf(mw - mnew); // p==0: pacc is 0
        mw = mnew;
#pragma unroll
        for (int k = 0; k < 4; ++k) {
            pacc[k].x *= scale; pacc[k].y *= scale;
            pacc[k].z *= scale; pacc[k].w *= scale;
        }
#pragma unroll
        for (int r = 0; r < 4; ++r) {
            const float e = expf(sc[r] - mw);
#pragma unroll
            for (int k = 0; k < 4; ++k) {
                pacc[k].x += e * c[r][k].x;
                pacc[k].y += e * c[r][k].y;
                pacc[k].z += e * c[r][k].z;
                pacc[k].w += e * c[r][k].w;
            }
        }
    }

    if (lane == 0) wmax[wave] = mw;
#pragma unroll
    for (int k = 0; k < 4; ++k) buf[wave * 256 + lane + 64 * k] = pacc[k];
    __syncthreads();

    const float mt = fmaxf(fmaxf(wmax[0], wmax[1]), fmaxf(wmax[2], wmax[3]));
    const float f0 = expf(wmax[0] - mt), f1 = expf(wmax[1] - mt);
    const float f2 = expf(wmax[2] - mt), f3 = expf(wmax[3] - mt);

    const int t = threadIdx.x;
    float4 v0 = buf[t], v1 = buf[256 + t], v2 = buf[512 + t], v3 = buf[768 + t];
    float4 sum;
    sum.x = (f0 * v0.x + f1 * v1.x) + (f2 * v2.x + f3 * v3.x);
    sum.y = (f0 * v0.y + f1 * v1.y) + (f2 * v2.y + f3 * v3.y);
    sum.z = (f0 * v0.z + f1 * v1.z) + (f2 * v2.z + f3 * v3.z);
    sum.w = (f0 * v0.w + f1 * v1.w) + (f2 * v2.w + f3 * v3.w);
    partial[((size_t)b * NT + tile) * 256 + t] = sum;
}

// ---------------------------------------------------------------------------
// Kernel B: grid (4, B) = 128 blocks. Block (bx, b):
//   1. full softmax over scores row (duplicated 4x per row — 8 KB, L3-hot)
//   2. alphas = min(parent, softmax) (written by bx==0 only); compact clipped
//      rows (alpha > parent) — E[#clipped] ~ 1 per row, capacity Sq exact.
//   3. for its 64 float4 columns: summary = sum_tile exp(m_tile-m)/Z *
//      partial[tile]  -  sum_clipped g * ctx_row. Tiles split across the 4
//      waves, combined in LDS.
// ---------------------------------------------------------------------------
__global__ __launch_bounds__(256) void finalize_kernel(
    const float* __restrict__ ctx, const float* __restrict__ scores,
    const float* __restrict__ prevatts, const int* __restrict__ parent_ptr,
    const float4* __restrict__ partial, float* __restrict__ alphas,
    float4* __restrict__ summary)
{
    const int b  = blockIdx.y;
    const int bx = blockIdx.x;      // column chunk: float4 cols [bx*64, bx*64+64)
    const int t  = threadIdx.x;

    __shared__ float  ssc[Sq];      // 8 KB: staged scores row
    __shared__ float  redA[4], redB[4];
    __shared__ float  ftile[NT];    // per-tile rescale factor
    __shared__ int    sidx[Sq];     // clipped-row indices (worst case all)
    __shared__ float  sg[Sq];       // clipped-row excess alpha-p
    __shared__ int    scount;
    __shared__ float4 rbuf[4][64];  // 4 KB cross-wave reduce

    if (t == 0) scount = 0;

    const float* srow = scores + (size_t)b * Sq;
    float vals[8];
    float m = -INFINITY;
#pragma unroll
    for (int i = 0; i < 8; ++i) {
        float v = srow[t + 256 * i];
        ssc[t + 256 * i] = v;
        vals[i] = v;
        m = fmaxf(m, v);
    }
#pragma unroll
    for (int off = 1; off < 64; off <<= 1)
        m = fmaxf(m, __shfl_xor(m, off, 64));
    if ((t & 63) == 0) redA[t >> 6] = m;
    __syncthreads();                       // covers ssc writes + scount init
    m = fmaxf(fmaxf(redA[0], redA[1]), fmaxf(redA[2], redA[3]));

    float sum = 0.f;
#pragma unroll
    for (int i = 0; i < 8; ++i) {
        vals[i] = expf(vals[i] - m);
        sum += vals[i];
    }
#pragma unroll
    for (int off = 1; off < 64; off <<= 1)
        sum += __shfl_xor(sum, off, 64);
    if ((t & 63) == 0) redB[t >> 6] = sum;
    __syncthreads();
    sum = (redB[0] + redB[1]) + (redB[2] + redB[3]);
    const float invZ = 1.0f / sum;

    // per-tile rescale factor: exp(m_tile - m) / Z  (m_tile from bit-exact ssc)
    if (t < NT) {
        float tm = -INFINITY;
#pragma unroll
        for (int i = 0; i < TILE; ++i) tm = fmaxf(tm, ssc[t * TILE + i]);
        ftile[t] = expf(tm - m) * invZ;
    }

    // alphas (bx==0 only) + compaction of clipped rows (all blocks, identical)
    const float* par = prevatts + ((size_t)b * Tq + parent_ptr[b]) * Sq;
#pragma unroll
    for (int i = 0; i < 8; ++i) {
        const int s = t + 256 * i;
        const float a = vals[i] * invZ;
        const float p = par[s];
        if (bx == 0) alphas[(size_t)b * Sq + s] = fminf(p, a);
        const float g = a - p;
        if (g > 0.f) {
            int pos = atomicAdd(&scount, 1);
            sidx[pos] = s;
            sg[pos]  = g;
        }
    }
    __syncthreads();                       // covers ftile, sidx/sg, scount

    // partial reduce over this block's 64 columns; tiles split across waves
    const int l   = t & 63;
    const int w   = t >> 6;
    const int col = bx * 64 + l;
    const float4* pp = partial + (size_t)b * NT * 256;
    float4 acc = make_float4(0.f, 0.f, 0.f, 0.f);
#pragma unroll
    for (int tile = w; tile < NT; tile += 4) {
        const float f = ftile[tile];
        float4 v = pp[(size_t)tile * 256 + col];
        acc.x += f * v.x;
        acc.y += f * v.y;
        acc.z += f * v.z;
        acc.w += f * v.w;
    }
    rbuf[w][l] = acc;
    __syncthreads();

    if (w == 0) {
        float4 a0 = rbuf[0][l], a1 = rbuf[1][l], a2 = rbuf[2][l], a3 = rbuf[3][l];
        acc.x = (a0.x + a1.x) + (a2.x + a3.x);
        acc.y = (a0.y + a1.y) + (a2.y + a3.y);
        acc.z = (a0.z + a1.z) + (a2.z + a3.z);
        acc.w = (a0.w + a1.w) + (a2.w + a3.w);
        const int cnt = scount;
        const float4* cb = (const float4*)(ctx + (size_t)b * Sq * Dq);
        for (int i = 0; i < cnt; ++i) {
            const int   s = sidx[i];
            const float g = sg[i];
            float4 v = cb[(size_t)s * 256 + col];
            acc.x -= g * v.x;
            acc.y -= g * v.y;
            acc.z -= g * v.z;
            acc.w -= g * v.w;
        }
        summary[b * 256 + col] = acc;
    }
}

extern "C" void kernel_launch(void* const* d_in, const int* in_sizes, int n_in,
                              void* d_out, int out_size, void* d_ws, size_t ws_size,
                              hipStream_t stream)
{
    const float* qry        = (const float*)d_in[0];
    const float* ctx        = (const float*)d_in[1];
    const float* mask       = (const float*)d_in[2];
    const float* prevatts   = (const float*)d_in[3];
    const int*   parent_ptr = (const int*)d_in[4];

    float* out     = (float*)d_out;
    float* alphas  = out;                      // B*S = 65536
    float* summary = out + Bq * Sq;            // B*D = 32768
    float* scores  = out + Bq * Sq + Bq * Dq;  // B*S = 65536

    float4* partial = (float4*)d_ws;           // B*NT*D floats = 4 MB

    fused_scores_partial_kernel<<<dim3(NT, Bq), 256, 0, stream>>>(
        qry, ctx, mask, scores, partial);
    finalize_kernel<<<dim3(4, Bq), 256, 0, stream>>>(
        ctx, scores, prevatts, parent_ptr, partial, alphas, (float4*)summary);
}

// Round 6
// 373.824 us; speedup vs baseline: 1.2209x; 1.2209x over previous
//
#include <hip/hip_runtime.h>
#include <math.h>

#define Bq 32
#define Sq 2048
#define Dq 1024
#define Tq 8
#define TILE 32            // S-rows per block in kernel A
#define NT (Sq / TILE)     // 64 tiles per batch row

// ---------------------------------------------------------------------------
// Kernel A: for each 32-row tile of (b):
//   scores[b,s] = dot(qry[b,:], ctx[b,s,:]) + log(mask[b,s])   (written out)
//   partial[b,tile,:] = sum_{s in tile} exp(scores[s] - m_tile) * ctx[b,s,:]
// Each wave owns 8 rows as two 4-row register-resident chunks with online
// max-rescale; cross-wave combine rescales by exp(m_wave - m_tile).
// ctx is read from HBM exactly once for the whole problem.
// NOTE (R5 post-mortem): do NOT raise TILE or pin min-occupancy here — the
// c[4][4] tile needs ~64 VGPRs live and __launch_bounds__(256,4) at TILE=64
// made the allocator collapse to 64 VGPRs and spill 190 MB to scratch.
// Grid (NT, B) = (64, 32) = 2048 blocks, block 256 (4 waves).
// ---------------------------------------------------------------------------
__global__ __launch_bounds__(256) void fused_scores_partial_kernel(
    const float* __restrict__ qry, const float* __restrict__ ctx,
    const float* __restrict__ mask, float* __restrict__ scores,
    float4* __restrict__ partial)
{
    const int b    = blockIdx.y;
    const int tile = blockIdx.x;
    const int s0   = tile * TILE;
    const int wave = threadIdx.x >> 6;
    const int lane = threadIdx.x & 63;

    __shared__ float  wmax[4];
    __shared__ float4 buf[4 * 256];    // 16 KB wave-partial exchange

    const float4* q4 = (const float4*)(qry + (size_t)b * Dq);
    float4 q[4];
#pragma unroll
    for (int k = 0; k < 4; ++k) q[k] = q4[lane + 64 * k];

    float4 pacc[4];
#pragma unroll
    for (int k = 0; k < 4; ++k) pacc[k] = make_float4(0.f, 0.f, 0.f, 0.f);
    float mw = -INFINITY;

#pragma unroll
    for (int p = 0; p < 2; ++p) {
        const int sbase = s0 + wave * 8 + p * 4;

        float4 c[4][4];
#pragma unroll
        for (int r = 0; r < 4; ++r) {
            const float4* c4 = (const float4*)(ctx + ((size_t)b * Sq + sbase + r) * Dq);
#pragma unroll
            for (int k = 0; k < 4; ++k) c[r][k] = c4[lane + 64 * k];
        }

        float sc[4];
#pragma unroll
        for (int r = 0; r < 4; ++r) {
            float acc = 0.f;
#pragma unroll
            for (int k = 0; k < 4; ++k)
                acc += q[k].x * c[r][k].x + q[k].y * c[r][k].y
                     + q[k].z * c[r][k].z + q[k].w * c[r][k].w;
#pragma unroll
            for (int off = 1; off < 64; off <<= 1)   // butterfly: all lanes get sum
                acc += __shfl_xor(acc, off, 64);
            acc += logf(mask[(size_t)b * Sq + sbase + r]);
            sc[r] = acc;
            if (lane == 0) scores[(size_t)b * Sq + sbase + r] = acc;
        }

        float mc = fmaxf(fmaxf(sc[0], sc[1]), fmaxf(sc[2], sc[3]));
        const float mnew = fmaxf(mw, mc);
        const float scale = (p == 0) ? 0.f : expf(mw - mnew); // p==0: pacc is 0
        mw = mnew;
#pragma unroll
        for (int k = 0; k < 4; ++k) {
            pacc[k].x *= scale; pacc[k].y *= scale;
            pacc[k].z *= scale; pacc[k].w *= scale;
        }
#pragma unroll
        for (int r = 0; r < 4; ++r) {
            const float e = expf(sc[r] - mw);
#pragma unroll
            for (int k = 0; k < 4; ++k) {
                pacc[k].x += e * c[r][k].x;
                pacc[k].y += e * c[r][k].y;
                pacc[k].z += e * c[r][k].z;
                pacc[k].w += e * c[r][k].w;
            }
        }
    }

    if (lane == 0) wmax[wave] = mw;
#pragma unroll
    for (int k = 0; k < 4; ++k) buf[wave * 256 + lane + 64 * k] = pacc[k];
    __syncthreads();

    const float mt = fmaxf(fmaxf(wmax[0], wmax[1]), fmaxf(wmax[2], wmax[3]));
    const float f0 = expf(wmax[0] - mt), f1 = expf(wmax[1] - mt);
    const float f2 = expf(wmax[2] - mt), f3 = expf(wmax[3] - mt);

    const int t = threadIdx.x;
    float4 v0 = buf[t], v1 = buf[256 + t], v2 = buf[512 + t], v3 = buf[768 + t];
    float4 sum;
    sum.x = (f0 * v0.x + f1 * v1.x) + (f2 * v2.x + f3 * v3.x);
    sum.y = (f0 * v0.y + f1 * v1.y) + (f2 * v2.y + f3 * v3.y);
    sum.z = (f0 * v0.z + f1 * v1.z) + (f2 * v2.z + f3 * v3.z);
    sum.w = (f0 * v0.w + f1 * v1.w) + (f2 * v2.w + f3 * v3.w);
    partial[((size_t)b * NT + tile) * 256 + t] = sum;
}

// ---------------------------------------------------------------------------
// Kernel B: grid (4, B) = 128 blocks. Block (bx, b):
//   1. full softmax over scores row (duplicated 4x per row — 8 KB, L3-hot)
//   2. alphas = min(parent, softmax) (written by bx==0 only); compact clipped
//      rows (alpha > parent) — E[#clipped] ~ 1 per row, capacity Sq exact.
//   3. for its 64 float4 columns: summary = sum_tile exp(m_tile-m)/Z *
//      partial[tile]  -  sum_clipped g * ctx_row. Tiles split across the 4
//      waves, combined in LDS.
// ---------------------------------------------------------------------------
__global__ __launch_bounds__(256) void finalize_kernel(
    const float* __restrict__ ctx, const float* __restrict__ scores,
    const float* __restrict__ prevatts, const int* __restrict__ parent_ptr,
    const float4* __restrict__ partial, float* __restrict__ alphas,
    float4* __restrict__ summary)
{
    const int b  = blockIdx.y;
    const int bx = blockIdx.x;      // column chunk: float4 cols [bx*64, bx*64+64)
    const int t  = threadIdx.x;

    __shared__ float  ssc[Sq];      // 8 KB: staged scores row
    __shared__ float  redA[4], redB[4];
    __shared__ float  ftile[NT];    // per-tile rescale factor
    __shared__ int    sidx[Sq];     // clipped-row indices (worst case all)
    __shared__ float  sg[Sq];       // clipped-row excess alpha-p
    __shared__ int    scount;
    __shared__ float4 rbuf[4][64];  // 4 KB cross-wave reduce

    if (t == 0) scount = 0;

    const float* srow = scores + (size_t)b * Sq;
    float vals[8];
    float m = -INFINITY;
#pragma unroll
    for (int i = 0; i < 8; ++i) {
        float v = srow[t + 256 * i];
        ssc[t + 256 * i] = v;
        vals[i] = v;
        m = fmaxf(m, v);
    }
#pragma unroll
    for (int off = 1; off < 64; off <<= 1)
        m = fmaxf(m, __shfl_xor(m, off, 64));
    if ((t & 63) == 0) redA[t >> 6] = m;
    __syncthreads();                       // covers ssc writes + scount init
    m = fmaxf(fmaxf(redA[0], redA[1]), fmaxf(redA[2], redA[3]));

    float sum = 0.f;
#pragma unroll
    for (int i = 0; i < 8; ++i) {
        vals[i] = expf(vals[i] - m);
        sum += vals[i];
    }
#pragma unroll
    for (int off = 1; off < 64; off <<= 1)
        sum += __shfl_xor(sum, off, 64);
    if ((t & 63) == 0) redB[t >> 6] = sum;
    __syncthreads();
    sum = (redB[0] + redB[1]) + (redB[2] + redB[3]);
    const float invZ = 1.0f / sum;

    // per-tile rescale factor: exp(m_tile - m) / Z  (m_tile from bit-exact ssc)
    if (t < NT) {
        float tm = -INFINITY;
#pragma unroll
        for (int i = 0; i < TILE; ++i) tm = fmaxf(tm, ssc[t * TILE + i]);
        ftile[t] = expf(tm - m) * invZ;
    }

    // alphas (bx==0 only) + compaction of clipped rows (all blocks, identical)
    const float* par = prevatts + ((size_t)b * Tq + parent_ptr[b]) * Sq;
#pragma unroll
    for (int i = 0; i < 8; ++i) {
        const int s = t + 256 * i;
        const float a = vals[i] * invZ;
        const float p = par[s];
        if (bx == 0) alphas[(size_t)b * Sq + s] = fminf(p, a);
        const float g = a - p;
        if (g > 0.f) {
            int pos = atomicAdd(&scount, 1);
            sidx[pos] = s;
            sg[pos]  = g;
        }
    }
    __syncthreads();                       // covers ftile, sidx/sg, scount

    // partial reduce over this block's 64 columns; tiles split across waves
    const int l   = t & 63;
    const int w   = t >> 6;
    const int col = bx * 64 + l;
    const float4* pp = partial + (size_t)b * NT * 256;
    float4 acc = make_float4(0.f, 0.f, 0.f, 0.f);
#pragma unroll
    for (int tile = w; tile < NT; tile += 4) {
        const float f = ftile[tile];
        float4 v = pp[(size_t)tile * 256 + col];
        acc.x += f * v.x;
        acc.y += f * v.y;
        acc.z += f * v.z;
        acc.w += f * v.w;
    }
    rbuf[w][l] = acc;
    __syncthreads();

    if (w == 0) {
        float4 a0 = rbuf[0][l], a1 = rbuf[1][l], a2 = rbuf[2][l], a3 = rbuf[3][l];
        acc.x = (a0.x + a1.x) + (a2.x + a3.x);
        acc.y = (a0.y + a1.y) + (a2.y + a3.y);
        acc.z = (a0.z + a1.z) + (a2.z + a3.z);
        acc.w = (a0.w + a1.w) + (a2.w + a3.w);
        const int cnt = scount;
        const float4* cb = (const float4*)(ctx + (size_t)b * Sq * Dq);
        for (int i = 0; i < cnt; ++i) {
            const int   s = sidx[i];
            const float g = sg[i];
            float4 v = cb[(size_t)s * 256 + col];
            acc.x -= g * v.x;
            acc.y -= g * v.y;
            acc.z -= g * v.z;
            acc.w -= g * v.w;
        }
        summary[b * 256 + col] = acc;
    }
}

extern "C" void kernel_launch(void* const* d_in, const int* in_sizes, int n_in,
                              void* d_out, int out_size, void* d_ws, size_t ws_size,
                              hipStream_t stream)
{
    const float* qry        = (const float*)d_in[0];
    const float* ctx        = (const float*)d_in[1];
    const float* mask       = (const float*)d_in[2];
    const float* prevatts   = (const float*)d_in[3];
    const int*   parent_ptr = (const int*)d_in[4];

    float* out     = (float*)d_out;
    float* alphas  = out;                      // B*S = 65536
    float* summary = out + Bq * Sq;            // B*D = 32768
    float* scores  = out + Bq * Sq + Bq * Dq;  // B*S = 65536

    float4* partial = (float4*)d_ws;           // B*NT*D floats = 8 MB

    fused_scores_partial_kernel<<<dim3(NT, Bq), 256, 0, stream>>>(
        qry, ctx, mask, scores, partial);
    finalize_kernel<<<dim3(4, Bq), 256, 0, stream>>>(
        ctx, scores, prevatts, parent_ptr, partial, alphas, (float4*)summary);
}